// Round 7
// baseline (299.470 us; speedup 1.0000x reference)
//
#include <hip/hip_runtime.h>

typedef _Float16 f16;
typedef __attribute__((ext_vector_type(4))) _Float16 f16x4;
typedef __attribute__((ext_vector_type(8))) _Float16 f16x8;
typedef __attribute__((ext_vector_type(4))) float f32x4;

#define BATCH 8
#define NTOK 1025
#define DIM 768
#define HEADS 12
#define HD 64
#define MTOT (BATCH * NTOK)      // 8200
#define MPAD 8320                // 65*128
#define NQP2 1152                // q rows padded to 9*128
#define NKP 1088                 // kv rows padded to 17*64
#define NUMREL 3972

__device__ __forceinline__ int imin(int a, int b) { return a < b ? a : b; }

__device__ __forceinline__ void gl_lds16(const f16* g, f16* l) {
  __builtin_amdgcn_global_load_lds(
      (const __attribute__((address_space(1))) unsigned int*)g,
      (__attribute__((address_space(3))) unsigned int*)l, 16, 0, 0);
}

// ---------------------------------------------------------------------------
// Kernel C: f32 -> f16 cast, 3 arrays in one launch
// ---------------------------------------------------------------------------
__global__ __launch_bounds__(256) void cast3(const float* __restrict__ s0,
                                             f16* __restrict__ d0, int n0,
                                             const float* __restrict__ s1,
                                             f16* __restrict__ d1, int n1,
                                             const float* __restrict__ s2,
                                             f16* __restrict__ d2, int n2) {
  const float* s = (blockIdx.y == 0) ? s0 : (blockIdx.y == 1) ? s1 : s2;
  f16* d = (blockIdx.y == 0) ? d0 : (blockIdx.y == 1) ? d1 : d2;
  int n = (blockIdx.y == 0) ? n0 : (blockIdx.y == 1) ? n1 : n2;
  for (size_t i = ((size_t)blockIdx.x * 256 + threadIdx.x) * 8; i < (size_t)n;
       i += (size_t)gridDim.x * 256 * 8) {
    float4 a = *(const float4*)(s + i);
    float4 b = *(const float4*)(s + i + 4);
    f16x8 r;
    r[0] = (f16)a.x; r[1] = (f16)a.y; r[2] = (f16)a.z; r[3] = (f16)a.w;
    r[4] = (f16)b.x; r[5] = (f16)b.y; r[6] = (f16)b.z; r[7] = (f16)b.w;
    *(f16x8*)(d + i) = r;
  }
}

// ---------------------------------------------------------------------------
// Kernel 0: bias table in TRANSPOSED-S fragment order:
//   tbl[h][kt][q 0..1087][lg 0..3][c*4+r] = bias(q, kv=kt*64+c*16+lg*4+r)
// ---------------------------------------------------------------------------
__device__ __forceinline__ float rpb_bias(const float* __restrict__ rpb, int qg,
                                          int kg, int h) {
  int idx;
  if (kg == 0) {
    idx = (qg == 0) ? (NUMREL - 1) : (NUMREL - 2);
  } else if (qg == 0) {
    idx = NUMREL - 3;
  } else {
    int qq = imin(qg, 1024) - 1, kk = imin(kg, 1024) - 1;
    int di = (qq >> 5) - (kk >> 5);
    int dj = (qq & 31) - (kk & 31);
    idx = (di + 31) * 63 + (dj + 31);
  }
  return rpb[idx * HEADS + h];
}

__global__ __launch_bounds__(256) void bias_pre(const float* __restrict__ rpb,
                                                f16* __restrict__ tbl) {
  const int kt = blockIdx.x / 17;
  const int qb17 = blockIdx.x % 17;
  const int h = blockIdx.y;
  const int tid = threadIdx.x;
  const int q = qb17 * 64 + (tid >> 2);
  const int lg = tid & 3;
  f16 vals[16];
#pragma unroll
  for (int c = 0; c < 4; c++)
#pragma unroll
    for (int r = 0; r < 4; r++) {
      int kv = kt * 64 + c * 16 + lg * 4 + r;
      float v = (kv >= NTOK) ? -30000.f : rpb_bias(rpb, q, kv, h);
      vals[c * 4 + r] = (f16)v;
    }
  size_t off = ((((size_t)h * 17 + kt) * NKP + q) * 4 + lg) * 16;
  *(f16x8*)(tbl + off) = *(const f16x8*)(&vals[0]);
  *(f16x8*)(tbl + off + 8) = *(const f16x8*)(&vals[8]);
}

// ---------------------------------------------------------------------------
// Kernel 1: qkv = xh @ wh^T + [q_bias,0,v_bias]; split Q(scaled)/K/V^T.
// BK=64 (128-B rows: 8 chunks cover all 32 banks; XOR row&7 -> conflict-free),
// double-buffered DMA staging, 12 barriers total.
// ---------------------------------------------------------------------------
__global__ __launch_bounds__(256) void qkv_gemm(
    const f16* __restrict__ Ah, const f16* __restrict__ Bh,
    const float* __restrict__ q_bias, const float* __restrict__ v_bias,
    f16* __restrict__ qb, f16* __restrict__ kb, f16* __restrict__ vtb) {
  __shared__ f16 As[2][128][64];  // 16 KB per buffer
  __shared__ f16 Bs[2][128][64];
  const int tid = threadIdx.x;
  const int lane = tid & 63, w = tid >> 6;
  const int wm = w >> 1, wn = w & 1;
  const int lr = lane & 15, lg = lane >> 4;
  const int tM = blockIdx.x;  // 0..64
  const int tN = blockIdx.y;  // 0..17
  const int r8 = lane >> 3;             // 0..7 (row within 8-row DMA slab)
  const int swch = (lane & 7) ^ r8;     // 8-chunk XOR swizzle (global side)
  const int lr7 = lr & 7;

  const f16* Ab = Ah + ((size_t)tM * 128 + r8) * DIM + swch * 8;
  const f16* Bb = Bh + ((size_t)tN * 128 + r8) * DIM + swch * 8;

#pragma unroll
  for (int pp = 0; pp < 4; pp++) {
    int rowb = w * 32 + pp * 8;
    gl_lds16(Ab + (size_t)rowb * DIM, &As[0][rowb][0]);
    gl_lds16(Bb + (size_t)rowb * DIM, &Bs[0][rowb][0]);
  }

  f32x4 acc[4][4] = {};

  for (int kt = 0; kt < 12; kt++) {
    const int bi = kt & 1;
    __syncthreads();  // structural vmcnt(0): tile-kt DMA complete
    if (kt + 1 < 12) {
#pragma unroll
      for (int pp = 0; pp < 4; pp++) {
        int rowb = w * 32 + pp * 8;
        gl_lds16(Ab + (size_t)rowb * DIM + (kt + 1) * 64, &As[bi ^ 1][rowb][0]);
        gl_lds16(Bb + (size_t)rowb * DIM + (kt + 1) * 64, &Bs[bi ^ 1][rowb][0]);
      }
    }
#pragma unroll
    for (int ks = 0; ks < 2; ks++) {
      f16x8 af[4], bf[4];
      int rc = ((ks * 4 + lg) ^ lr7) * 8;
#pragma unroll
      for (int i = 0; i < 4; i++) {
        af[i] = *(const f16x8*)(&As[bi][wm * 64 + i * 16 + lr][rc]);
        bf[i] = *(const f16x8*)(&Bs[bi][wn * 64 + i * 16 + lr][rc]);
      }
#pragma unroll
      for (int mi = 0; mi < 4; mi++)
#pragma unroll
        for (int ni = 0; ni < 4; ni++)
          acc[mi][ni] = __builtin_amdgcn_mfma_f32_16x16x32_f16(
              af[mi], bf[ni], acc[mi][ni], 0, 0, 0);
    }
  }

  const int which = tN / 6;
  const int nb = tN % 6;
#pragma unroll
  for (int mi = 0; mi < 4; mi++) {
#pragma unroll
    for (int ni = 0; ni < 4; ni++) {
      int ncol = nb * 128 + wn * 64 + ni * 16 + lr;  // 0..767
      int h = ncol >> 6, dd = ncol & 63;
      float bias = 0.f;
      if (which == 0) bias = q_bias[ncol];
      if (which == 2) bias = v_bias[ncol];
#pragma unroll
      for (int r = 0; r < 4; r++) {
        int m = tM * 128 + wm * 64 + mi * 16 + lg * 4 + r;
        if (m >= MTOT) continue;
        int b = m / NTOK;
        int t = m - b * NTOK;
        int bh = b * HEADS + h;
        float v = acc[mi][ni][r] + bias;
        if (which == 0)
          qb[((size_t)bh * NQP2 + t) * HD + dd] = (f16)(v * 0.125f);
        else if (which == 1)
          kb[((size_t)bh * NKP + t) * HD + dd] = (f16)v;
        else
          vtb[((size_t)bh * HD + dd) * NKP + t] = (f16)v;
      }
    }
  }
}

// ---------------------------------------------------------------------------
// Kernel 2: fused flash attention (unchanged from round 6 — control)
// ---------------------------------------------------------------------------
__global__ __launch_bounds__(256) void attn_kernel(
    const f16* __restrict__ qb, const f16* __restrict__ kb,
    const f16* __restrict__ vtb, const f16* __restrict__ tbl,
    f16* __restrict__ ob) {
  __shared__ f16 Ks[2][64][64];
  __shared__ f16 Vs[2][64][64];
  __shared__ f16 Plds[4][16][72];
  const int tid = threadIdx.x;
  const int lane = tid & 63, w = tid >> 6;
  const int lr = lane & 15, lg = lane >> 4;
  const int qblk = blockIdx.x % 9;
  const int bh = blockIdx.x / 9;
  const int h = bh % HEADS, b = bh / HEADS;
  const int q0 = qblk * 128 + w * 32;

  const f16* kbase = kb + (size_t)bh * NKP * HD;
  const f16* vbase = vtb + (size_t)bh * HD * NKP;

  const int srow8 = lane >> 3;
  const int swch = (lane & 7) ^ srow8;

#pragma unroll
  for (int pp = 0; pp < 2; pp++) {
    int p = w * 2 + pp;
    int row = p * 8 + srow8;
    gl_lds16(kbase + (size_t)row * HD + swch * 8, &Ks[0][p * 8][0]);
    gl_lds16(vbase + (size_t)row * NKP + swch * 8, &Vs[0][p * 8][0]);
  }

  f16x8 aq[2][2];
#pragma unroll
  for (int g = 0; g < 2; g++) {
    const f16* qp = qb + ((size_t)bh * NQP2 + q0 + g * 16 + lr) * HD + lg * 8;
    aq[g][0] = *(const f16x8*)(qp);
    aq[g][1] = *(const f16x8*)(qp + 32);
  }

  const f16* bp[2];
#pragma unroll
  for (int g = 0; g < 2; g++) {
    int qt = imin(q0 + g * 16 + lr, NKP - 1);
    bp[g] = tbl + (((size_t)h * 17 * NKP + qt) * 4 + lg) * 16;
  }
  f16x8 bb[2][2];
#pragma unroll
  for (int g = 0; g < 2; g++) {
    bb[g][0] = *(const f16x8*)(bp[g]);
    bb[g][1] = *(const f16x8*)(bp[g] + 8);
  }

  float lsum[2] = {0.f, 0.f};
  f32x4 oacc[2][4] = {};
  const int sw8 = lr & 7;
  const size_t ktstride = (size_t)NKP * 64;

  for (int kt = 0; kt < 17; kt++) {
    const int bi = kt & 1;
    __syncthreads();
    if (kt + 1 < 17) {
#pragma unroll
      for (int pp = 0; pp < 2; pp++) {
        int p = w * 2 + pp;
        int row = p * 8 + srow8;
        gl_lds16(kbase + (size_t)((kt + 1) * 64 + row) * HD + swch * 8,
                 &Ks[bi ^ 1][p * 8][0]);
        gl_lds16(vbase + (size_t)row * NKP + (kt + 1) * 64 + swch * 8,
                 &Vs[bi ^ 1][p * 8][0]);
      }
    }
    f16x8 nb[2][2] = {};
    if (kt + 1 < 17) {
#pragma unroll
      for (int g = 0; g < 2; g++) {
        const f16* p8 = bp[g] + (size_t)(kt + 1) * ktstride;
        nb[g][0] = *(const f16x8*)(p8);
        nb[g][1] = *(const f16x8*)(p8 + 8);
      }
    }
    f32x4 s[2][4];
#pragma unroll
    for (int g = 0; g < 2; g++)
#pragma unroll
      for (int c = 0; c < 4; c++) {
        const f16* src = (const f16*)&bb[g][c >> 1];
#pragma unroll
        for (int r = 0; r < 4; r++) s[g][c][r] = (float)src[(c & 1) * 4 + r];
      }
#pragma unroll
    for (int c = 0; c < 4; c++) {
      f16x8 kf0 = *(const f16x8*)(&Ks[bi][c * 16 + lr][(lg ^ sw8) * 8]);
      f16x8 kf1 = *(const f16x8*)(&Ks[bi][c * 16 + lr][((lg + 4) ^ sw8) * 8]);
      s[0][c] = __builtin_amdgcn_mfma_f32_16x16x32_f16(kf0, aq[0][0], s[0][c], 0, 0, 0);
      s[0][c] = __builtin_amdgcn_mfma_f32_16x16x32_f16(kf1, aq[0][1], s[0][c], 0, 0, 0);
      s[1][c] = __builtin_amdgcn_mfma_f32_16x16x32_f16(kf0, aq[1][0], s[1][c], 0, 0, 0);
      s[1][c] = __builtin_amdgcn_mfma_f32_16x16x32_f16(kf1, aq[1][1], s[1][c], 0, 0, 0);
    }
#pragma unroll
    for (int g = 0; g < 2; g++)
#pragma unroll
      for (int c = 0; c < 4; c++)
#pragma unroll
        for (int r = 0; r < 4; r++) {
          float p = __expf(s[g][c][r]);
          s[g][c][r] = p;
          lsum[g] += p;
        }
    f16x8 ap[2][2];
#pragma unroll
    for (int g = 0; g < 2; g++) {
#pragma unroll
      for (int c = 0; c < 4; c++) {
        f16x4 pk;
        pk[0] = (f16)s[g][c][0];
        pk[1] = (f16)s[g][c][1];
        pk[2] = (f16)s[g][c][2];
        pk[3] = (f16)s[g][c][3];
        *(f16x4*)(&Plds[w][lr][c * 16 + lg * 4]) = pk;
      }
      ap[g][0] = *(const f16x8*)(&Plds[w][lr][lg * 8]);
      ap[g][1] = *(const f16x8*)(&Plds[w][lr][32 + lg * 8]);
    }
#pragma unroll
    for (int dblk = 0; dblk < 4; dblk++) {
      f16x8 vf0 = *(const f16x8*)(&Vs[bi][dblk * 16 + lr][(lg ^ sw8) * 8]);
      f16x8 vf1 = *(const f16x8*)(&Vs[bi][dblk * 16 + lr][((lg + 4) ^ sw8) * 8]);
      oacc[0][dblk] = __builtin_amdgcn_mfma_f32_16x16x32_f16(ap[0][0], vf0, oacc[0][dblk], 0, 0, 0);
      oacc[0][dblk] = __builtin_amdgcn_mfma_f32_16x16x32_f16(ap[0][1], vf1, oacc[0][dblk], 0, 0, 0);
      oacc[1][dblk] = __builtin_amdgcn_mfma_f32_16x16x32_f16(ap[1][0], vf0, oacc[1][dblk], 0, 0, 0);
      oacc[1][dblk] = __builtin_amdgcn_mfma_f32_16x16x32_f16(ap[1][1], vf1, oacc[1][dblk], 0, 0, 0);
    }
#pragma unroll
    for (int g = 0; g < 2; g++) {
      bb[g][0] = nb[g][0];
      bb[g][1] = nb[g][1];
    }
  }
#pragma unroll
  for (int g = 0; g < 2; g++) {
    float ls = lsum[g];
    ls += __shfl_xor(ls, 16);
    ls += __shfl_xor(ls, 32);
    float inv[4];
#pragma unroll
    for (int r = 0; r < 4; r++) inv[r] = 1.f / __shfl(ls, lg * 4 + r);
#pragma unroll
    for (int dblk = 0; dblk < 4; dblk++)
#pragma unroll
      for (int r = 0; r < 4; r++) {
        int qg = q0 + g * 16 + lg * 4 + r;
        if (qg >= NTOK) continue;
        float v = oacc[g][dblk][r] * inv[r];
        ob[((size_t)(b * NTOK + qg)) * DIM + h * HD + dblk * 16 + lr] = (f16)v;
      }
  }
}

// ---------------------------------------------------------------------------
// Kernel 3: out = ob @ pwh^T + proj_b. 128x128 tile, BK=64 dbuf (same
// structure as qkv_gemm), grid 65x6.
// ---------------------------------------------------------------------------
__global__ __launch_bounds__(256) void proj_gemm(const f16* __restrict__ Ah,
                                                 const f16* __restrict__ Bh,
                                                 const float* __restrict__ pb,
                                                 float* __restrict__ out) {
  __shared__ f16 As[2][128][64];
  __shared__ f16 Bs[2][128][64];
  const int tid = threadIdx.x;
  const int lane = tid & 63, w = tid >> 6;
  const int wm = w >> 1, wn = w & 1;
  const int lr = lane & 15, lg = lane >> 4;
  const int tM = blockIdx.x;  // 0..64
  const int tN = blockIdx.y;  // 0..5
  const int r8 = lane >> 3;
  const int swch = (lane & 7) ^ r8;
  const int lr7 = lr & 7;

  const f16* Ab = Ah + ((size_t)tM * 128 + r8) * DIM + swch * 8;
  const f16* Bb = Bh + ((size_t)tN * 128 + r8) * DIM + swch * 8;

#pragma unroll
  for (int pp = 0; pp < 4; pp++) {
    int rowb = w * 32 + pp * 8;
    gl_lds16(Ab + (size_t)rowb * DIM, &As[0][rowb][0]);
    gl_lds16(Bb + (size_t)rowb * DIM, &Bs[0][rowb][0]);
  }

  f32x4 acc[4][4] = {};

  for (int kt = 0; kt < 12; kt++) {
    const int bi = kt & 1;
    __syncthreads();
    if (kt + 1 < 12) {
#pragma unroll
      for (int pp = 0; pp < 4; pp++) {
        int rowb = w * 32 + pp * 8;
        gl_lds16(Ab + (size_t)rowb * DIM + (kt + 1) * 64, &As[bi ^ 1][rowb][0]);
        gl_lds16(Bb + (size_t)rowb * DIM + (kt + 1) * 64, &Bs[bi ^ 1][rowb][0]);
      }
    }
#pragma unroll
    for (int ks = 0; ks < 2; ks++) {
      f16x8 af[4], bf[4];
      int rc = ((ks * 4 + lg) ^ lr7) * 8;
#pragma unroll
      for (int i = 0; i < 4; i++) {
        af[i] = *(const f16x8*)(&As[bi][wm * 64 + i * 16 + lr][rc]);
        bf[i] = *(const f16x8*)(&Bs[bi][wn * 64 + i * 16 + lr][rc]);
      }
#pragma unroll
      for (int mi = 0; mi < 4; mi++)
#pragma unroll
        for (int ni = 0; ni < 4; ni++)
          acc[mi][ni] = __builtin_amdgcn_mfma_f32_16x16x32_f16(
              af[mi], bf[ni], acc[mi][ni], 0, 0, 0);
    }
  }

#pragma unroll
  for (int mi = 0; mi < 4; mi++) {
#pragma unroll
    for (int ni = 0; ni < 4; ni++) {
      int n = tN * 128 + wn * 64 + ni * 16 + lr;
      float bias = pb[n];
#pragma unroll
      for (int r = 0; r < 4; r++) {
        int m = tM * 128 + wm * 64 + mi * 16 + lg * 4 + r;
        if (m >= MTOT) continue;
        out[(size_t)m * DIM + n] = acc[mi][ni][r] + bias;
      }
    }
  }
}

extern "C" void kernel_launch(void* const* d_in, const int* in_sizes, int n_in,
                              void* d_out, int out_size, void* d_ws,
                              size_t ws_size, hipStream_t stream) {
  const float* x = (const float*)d_in[0];
  const float* qkv_w = (const float*)d_in[1];
  const float* q_bias = (const float*)d_in[2];
  const float* v_bias = (const float*)d_in[3];
  const float* rpb = (const float*)d_in[4];
  const float* proj_w = (const float*)d_in[5];
  const float* proj_b = (const float*)d_in[6];
  float* out = (float*)d_out;

  f16* xh = (f16*)d_ws;                        // [MPAD,768]
  f16* wh = xh + (size_t)MPAD * DIM;           // [2304,768]
  f16* pwh = wh + (size_t)3 * DIM * DIM;       // [768,768]
  f16* qb = pwh + (size_t)DIM * DIM;           // [96,1152,64]
  f16* kb = qb + (size_t)BATCH * HEADS * NQP2 * HD;
  f16* vtb = kb + (size_t)BATCH * HEADS * NKP * HD;
  f16* ob = vtb + (size_t)BATCH * HEADS * NKP * HD;  // [MPAD,768]
  f16* tbl = ob + (size_t)MPAD * DIM;          // [12,17,1088,4,16]

  cast3<<<dim3(1024, 3), 256, 0, stream>>>(
      x, xh, MTOT * DIM, qkv_w, wh, 3 * DIM * DIM, proj_w, pwh, DIM * DIM);
  bias_pre<<<dim3(17 * 17, HEADS), 256, 0, stream>>>(rpb, tbl);
  qkv_gemm<<<dim3(65, 18), 256, 0, stream>>>(xh, wh, q_bias, v_bias, qb, kb,
                                             vtb);
  attn_kernel<<<dim3(BATCH * HEADS * 9), 256, 0, stream>>>(qb, kb, vtb, tbl,
                                                           ob);
  proj_gemm<<<dim3(65, 6), 256, 0, stream>>>(ob, pwh, proj_b, out);
}

// Round 9
// 292.664 us; speedup vs baseline: 1.0233x; 1.0233x over previous
//
#include <hip/hip_runtime.h>

typedef _Float16 f16;
typedef __attribute__((ext_vector_type(4))) _Float16 f16x4;
typedef __attribute__((ext_vector_type(8))) _Float16 f16x8;
typedef __attribute__((ext_vector_type(4))) float f32x4;

#define BATCH 8
#define NTOK 1025
#define DIM 768
#define HEADS 12
#define HD 64
#define MTOT (BATCH * NTOK)      // 8200
#define MPAD 8320                // 65*128
#define NQP2 1152                // q rows padded to 9*128
#define NKP 1088                 // kv rows padded to 17*64
#define NUMREL 3972

// Explicit DMA drain before barrier: the dbuf correctness REQUIRES vmcnt(0)
// between global_load_lds issue and s_barrier; do not rely on the compiler's
// implicit emission (round-8 nondeterministic divergence).
#define DMA_FENCE asm volatile("s_waitcnt vmcnt(0)" ::: "memory")

__device__ __forceinline__ int imin(int a, int b) { return a < b ? a : b; }

__device__ __forceinline__ void gl_lds16(const f16* g, f16* l) {
  __builtin_amdgcn_global_load_lds(
      (const __attribute__((address_space(1))) unsigned int*)g,
      (__attribute__((address_space(3))) unsigned int*)l, 16, 0, 0);
}

// ---------------------------------------------------------------------------
// Kernel C: f32 -> f16 cast, 3 arrays in one launch
// ---------------------------------------------------------------------------
__global__ __launch_bounds__(256) void cast3(const float* __restrict__ s0,
                                             f16* __restrict__ d0, int n0,
                                             const float* __restrict__ s1,
                                             f16* __restrict__ d1, int n1,
                                             const float* __restrict__ s2,
                                             f16* __restrict__ d2, int n2) {
  const float* s = (blockIdx.y == 0) ? s0 : (blockIdx.y == 1) ? s1 : s2;
  f16* d = (blockIdx.y == 0) ? d0 : (blockIdx.y == 1) ? d1 : d2;
  int n = (blockIdx.y == 0) ? n0 : (blockIdx.y == 1) ? n1 : n2;
  for (size_t i = ((size_t)blockIdx.x * 256 + threadIdx.x) * 8; i < (size_t)n;
       i += (size_t)gridDim.x * 256 * 8) {
    float4 a = *(const float4*)(s + i);
    float4 b = *(const float4*)(s + i + 4);
    f16x8 r;
    r[0] = (f16)a.x; r[1] = (f16)a.y; r[2] = (f16)a.z; r[3] = (f16)a.w;
    r[4] = (f16)b.x; r[5] = (f16)b.y; r[6] = (f16)b.z; r[7] = (f16)b.w;
    *(f16x8*)(d + i) = r;
  }
}

// ---------------------------------------------------------------------------
// Kernel 0: bias table in TRANSPOSED-S fragment order:
//   tbl[h][kt][q 0..1087][lg 0..3][c*4+r] = bias(q, kv=kt*64+c*16+lg*4+r)
// ---------------------------------------------------------------------------
__device__ __forceinline__ float rpb_bias(const float* __restrict__ rpb, int qg,
                                          int kg, int h) {
  int idx;
  if (kg == 0) {
    idx = (qg == 0) ? (NUMREL - 1) : (NUMREL - 2);
  } else if (qg == 0) {
    idx = NUMREL - 3;
  } else {
    int qq = imin(qg, 1024) - 1, kk = imin(kg, 1024) - 1;
    int di = (qq >> 5) - (kk >> 5);
    int dj = (qq & 31) - (kk & 31);
    idx = (di + 31) * 63 + (dj + 31);
  }
  return rpb[idx * HEADS + h];
}

__global__ __launch_bounds__(256) void bias_pre(const float* __restrict__ rpb,
                                                f16* __restrict__ tbl) {
  const int kt = blockIdx.x / 17;
  const int qb17 = blockIdx.x % 17;
  const int h = blockIdx.y;
  const int tid = threadIdx.x;
  const int q = qb17 * 64 + (tid >> 2);
  const int lg = tid & 3;
  f16 vals[16];
#pragma unroll
  for (int c = 0; c < 4; c++)
#pragma unroll
    for (int r = 0; r < 4; r++) {
      int kv = kt * 64 + c * 16 + lg * 4 + r;
      float v = (kv >= NTOK) ? -30000.f : rpb_bias(rpb, q, kv, h);
      vals[c * 4 + r] = (f16)v;
    }
  size_t off = ((((size_t)h * 17 + kt) * NKP + q) * 4 + lg) * 16;
  *(f16x8*)(tbl + off) = *(const f16x8*)(&vals[0]);
  *(f16x8*)(tbl + off + 8) = *(const f16x8*)(&vals[8]);
}

// ---------------------------------------------------------------------------
// Kernel 1: qkv = xh @ wh^T + [q_bias,0,v_bias]; split Q(scaled)/K/V^T.
// BK=64 dbuf DMA staging. GRID (18,65): tN fast -> A-tile sharers adjacent.
// ---------------------------------------------------------------------------
__global__ __launch_bounds__(256) void qkv_gemm(
    const f16* __restrict__ Ah, const f16* __restrict__ Bh,
    const float* __restrict__ q_bias, const float* __restrict__ v_bias,
    f16* __restrict__ qb, f16* __restrict__ kb, f16* __restrict__ vtb) {
  __shared__ f16 As[2][128][64];  // 16 KB per buffer
  __shared__ f16 Bs[2][128][64];
  const int tid = threadIdx.x;
  const int lane = tid & 63, w = tid >> 6;
  const int wm = w >> 1, wn = w & 1;
  const int lr = lane & 15, lg = lane >> 4;
  const int tN = blockIdx.x;  // 0..17  (fast dim: A-tile sharers adjacent)
  const int tM = blockIdx.y;  // 0..64
  const int r8 = lane >> 3;             // 0..7 (row within 8-row DMA slab)
  const int swch = (lane & 7) ^ r8;     // 8-chunk XOR swizzle (global side)
  const int lr7 = lr & 7;

  const f16* Ab = Ah + ((size_t)tM * 128 + r8) * DIM + swch * 8;
  const f16* Bb = Bh + ((size_t)tN * 128 + r8) * DIM + swch * 8;

#pragma unroll
  for (int pp = 0; pp < 4; pp++) {
    int rowb = w * 32 + pp * 8;
    gl_lds16(Ab + (size_t)rowb * DIM, &As[0][rowb][0]);
    gl_lds16(Bb + (size_t)rowb * DIM, &Bs[0][rowb][0]);
  }

  f32x4 acc[4][4] = {};

  for (int kt = 0; kt < 12; kt++) {
    const int bi = kt & 1;
    DMA_FENCE;        // own DMA (tile kt) complete before barrier
    __syncthreads();  // all waves' DMA complete -> tile kt readable
    if (kt + 1 < 12) {
#pragma unroll
      for (int pp = 0; pp < 4; pp++) {
        int rowb = w * 32 + pp * 8;
        gl_lds16(Ab + (size_t)rowb * DIM + (kt + 1) * 64, &As[bi ^ 1][rowb][0]);
        gl_lds16(Bb + (size_t)rowb * DIM + (kt + 1) * 64, &Bs[bi ^ 1][rowb][0]);
      }
    }
#pragma unroll
    for (int ks = 0; ks < 2; ks++) {
      f16x8 af[4], bf[4];
      int rc = ((ks * 4 + lg) ^ lr7) * 8;
#pragma unroll
      for (int i = 0; i < 4; i++) {
        af[i] = *(const f16x8*)(&As[bi][wm * 64 + i * 16 + lr][rc]);
        bf[i] = *(const f16x8*)(&Bs[bi][wn * 64 + i * 16 + lr][rc]);
      }
#pragma unroll
      for (int mi = 0; mi < 4; mi++)
#pragma unroll
        for (int ni = 0; ni < 4; ni++)
          acc[mi][ni] = __builtin_amdgcn_mfma_f32_16x16x32_f16(
              af[mi], bf[ni], acc[mi][ni], 0, 0, 0);
    }
  }

  const int which = tN / 6;
  const int nb = tN % 6;
#pragma unroll
  for (int mi = 0; mi < 4; mi++) {
#pragma unroll
    for (int ni = 0; ni < 4; ni++) {
      int ncol = nb * 128 + wn * 64 + ni * 16 + lr;  // 0..767
      int h = ncol >> 6, dd = ncol & 63;
      float bias = 0.f;
      if (which == 0) bias = q_bias[ncol];
      if (which == 2) bias = v_bias[ncol];
#pragma unroll
      for (int r = 0; r < 4; r++) {
        int m = tM * 128 + wm * 64 + mi * 16 + lg * 4 + r;
        if (m >= MTOT) continue;
        int b = m / NTOK;
        int t = m - b * NTOK;
        int bh = b * HEADS + h;
        float v = acc[mi][ni][r] + bias;
        if (which == 0)
          qb[((size_t)bh * NQP2 + t) * HD + dd] = (f16)(v * 0.125f);
        else if (which == 1)
          kb[((size_t)bh * NKP + t) * HD + dd] = (f16)v;
        else
          vtb[((size_t)bh * HD + dd) * NKP + t] = (f16)v;
      }
    }
  }
}

// ---------------------------------------------------------------------------
// Kernel 2: fused flash attention. Block ID = b + 8*qblk + 72*h: the 8
// bias-slab sharers (same h,qblk) adjacent; 9 K/V sharers within 72 blocks.
// ---------------------------------------------------------------------------
__global__ __launch_bounds__(256) void attn_kernel(
    const f16* __restrict__ qb, const f16* __restrict__ kb,
    const f16* __restrict__ vtb, const f16* __restrict__ tbl,
    f16* __restrict__ ob) {
  __shared__ f16 Ks[2][64][64];
  __shared__ f16 Vs[2][64][64];
  __shared__ f16 Plds[4][16][72];
  const int tid = threadIdx.x;
  const int lane = tid & 63, w = tid >> 6;
  const int lr = lane & 15, lg = lane >> 4;
  const int b = blockIdx.x & 7;          // fastest: bias-slab sharers adjacent
  const int t9 = blockIdx.x >> 3;        // 0..107
  const int qblk = t9 % 9;
  const int h = t9 / 9;
  const int bh = b * HEADS + h;
  const int q0 = qblk * 128 + w * 32;

  const f16* kbase = kb + (size_t)bh * NKP * HD;
  const f16* vbase = vtb + (size_t)bh * HD * NKP;

  const int srow8 = lane >> 3;
  const int swch = (lane & 7) ^ srow8;

#pragma unroll
  for (int pp = 0; pp < 2; pp++) {
    int p = w * 2 + pp;
    int row = p * 8 + srow8;
    gl_lds16(kbase + (size_t)row * HD + swch * 8, &Ks[0][p * 8][0]);
    gl_lds16(vbase + (size_t)row * NKP + swch * 8, &Vs[0][p * 8][0]);
  }

  f16x8 aq[2][2];
#pragma unroll
  for (int g = 0; g < 2; g++) {
    const f16* qp = qb + ((size_t)bh * NQP2 + q0 + g * 16 + lr) * HD + lg * 8;
    aq[g][0] = *(const f16x8*)(qp);
    aq[g][1] = *(const f16x8*)(qp + 32);
  }

  const f16* bp[2];
#pragma unroll
  for (int g = 0; g < 2; g++) {
    int qt = imin(q0 + g * 16 + lr, NKP - 1);
    bp[g] = tbl + (((size_t)h * 17 * NKP + qt) * 4 + lg) * 16;
  }
  f16x8 bb[2][2];
#pragma unroll
  for (int g = 0; g < 2; g++) {
    bb[g][0] = *(const f16x8*)(bp[g]);
    bb[g][1] = *(const f16x8*)(bp[g] + 8);
  }

  float lsum[2] = {0.f, 0.f};
  f32x4 oacc[2][4] = {};
  const int sw8 = lr & 7;
  const size_t ktstride = (size_t)NKP * 64;

  for (int kt = 0; kt < 17; kt++) {
    const int bi = kt & 1;
    DMA_FENCE;        // own DMA (tile kt) complete before barrier
    __syncthreads();
    if (kt + 1 < 17) {
#pragma unroll
      for (int pp = 0; pp < 2; pp++) {
        int p = w * 2 + pp;
        int row = p * 8 + srow8;
        gl_lds16(kbase + (size_t)((kt + 1) * 64 + row) * HD + swch * 8,
                 &Ks[bi ^ 1][p * 8][0]);
        gl_lds16(vbase + (size_t)row * NKP + (kt + 1) * 64 + swch * 8,
                 &Vs[bi ^ 1][p * 8][0]);
      }
    }
    f16x8 nb[2][2] = {};
    if (kt + 1 < 17) {
#pragma unroll
      for (int g = 0; g < 2; g++) {
        const f16* p8 = bp[g] + (size_t)(kt + 1) * ktstride;
        nb[g][0] = *(const f16x8*)(p8);
        nb[g][1] = *(const f16x8*)(p8 + 8);
      }
    }
    f32x4 s[2][4];
#pragma unroll
    for (int g = 0; g < 2; g++)
#pragma unroll
      for (int c = 0; c < 4; c++) {
        const f16* src = (const f16*)&bb[g][c >> 1];
#pragma unroll
        for (int r = 0; r < 4; r++) s[g][c][r] = (float)src[(c & 1) * 4 + r];
      }
#pragma unroll
    for (int c = 0; c < 4; c++) {
      f16x8 kf0 = *(const f16x8*)(&Ks[bi][c * 16 + lr][(lg ^ sw8) * 8]);
      f16x8 kf1 = *(const f16x8*)(&Ks[bi][c * 16 + lr][((lg + 4) ^ sw8) * 8]);
      s[0][c] = __builtin_amdgcn_mfma_f32_16x16x32_f16(kf0, aq[0][0], s[0][c], 0, 0, 0);
      s[0][c] = __builtin_amdgcn_mfma_f32_16x16x32_f16(kf1, aq[0][1], s[0][c], 0, 0, 0);
      s[1][c] = __builtin_amdgcn_mfma_f32_16x16x32_f16(kf0, aq[1][0], s[1][c], 0, 0, 0);
      s[1][c] = __builtin_amdgcn_mfma_f32_16x16x32_f16(kf1, aq[1][1], s[1][c], 0, 0, 0);
    }
#pragma unroll
    for (int g = 0; g < 2; g++)
#pragma unroll
      for (int c = 0; c < 4; c++)
#pragma unroll
        for (int r = 0; r < 4; r++) {
          float p = __expf(s[g][c][r]);
          s[g][c][r] = p;
          lsum[g] += p;
        }
    f16x8 ap[2][2];
#pragma unroll
    for (int g = 0; g < 2; g++) {
#pragma unroll
      for (int c = 0; c < 4; c++) {
        f16x4 pk;
        pk[0] = (f16)s[g][c][0];
        pk[1] = (f16)s[g][c][1];
        pk[2] = (f16)s[g][c][2];
        pk[3] = (f16)s[g][c][3];
        *(f16x4*)(&Plds[w][lr][c * 16 + lg * 4]) = pk;
      }
      ap[g][0] = *(const f16x8*)(&Plds[w][lr][lg * 8]);
      ap[g][1] = *(const f16x8*)(&Plds[w][lr][32 + lg * 8]);
    }
#pragma unroll
    for (int dblk = 0; dblk < 4; dblk++) {
      f16x8 vf0 = *(const f16x8*)(&Vs[bi][dblk * 16 + lr][(lg ^ sw8) * 8]);
      f16x8 vf1 = *(const f16x8*)(&Vs[bi][dblk * 16 + lr][((lg + 4) ^ sw8) * 8]);
      oacc[0][dblk] = __builtin_amdgcn_mfma_f32_16x16x32_f16(ap[0][0], vf0, oacc[0][dblk], 0, 0, 0);
      oacc[0][dblk] = __builtin_amdgcn_mfma_f32_16x16x32_f16(ap[0][1], vf1, oacc[0][dblk], 0, 0, 0);
      oacc[1][dblk] = __builtin_amdgcn_mfma_f32_16x16x32_f16(ap[1][0], vf0, oacc[1][dblk], 0, 0, 0);
      oacc[1][dblk] = __builtin_amdgcn_mfma_f32_16x16x32_f16(ap[1][1], vf1, oacc[1][dblk], 0, 0, 0);
    }
#pragma unroll
    for (int g = 0; g < 2; g++) {
      bb[g][0] = nb[g][0];
      bb[g][1] = nb[g][1];
    }
  }
#pragma unroll
  for (int g = 0; g < 2; g++) {
    float ls = lsum[g];
    ls += __shfl_xor(ls, 16);
    ls += __shfl_xor(ls, 32);
    float inv[4];
#pragma unroll
    for (int r = 0; r < 4; r++) inv[r] = 1.f / __shfl(ls, lg * 4 + r);
#pragma unroll
    for (int dblk = 0; dblk < 4; dblk++)
#pragma unroll
      for (int r = 0; r < 4; r++) {
        int qg = q0 + g * 16 + lg * 4 + r;
        if (qg >= NTOK) continue;
        float v = oacc[g][dblk][r] * inv[r];
        ob[((size_t)(b * NTOK + qg)) * DIM + h * HD + dblk * 16 + lr] = (f16)v;
      }
  }
}

// ---------------------------------------------------------------------------
// Kernel 3: out = ob @ pwh^T + proj_b. 128x128 tile, BK=64 dbuf.
// GRID (6,65): tN fast -> A-tile sharers adjacent.
// ---------------------------------------------------------------------------
__global__ __launch_bounds__(256) void proj_gemm(const f16* __restrict__ Ah,
                                                 const f16* __restrict__ Bh,
                                                 const float* __restrict__ pb,
                                                 float* __restrict__ out) {
  __shared__ f16 As[2][128][64];
  __shared__ f16 Bs[2][128][64];
  const int tid = threadIdx.x;
  const int lane = tid & 63, w = tid >> 6;
  const int wm = w >> 1, wn = w & 1;
  const int lr = lane & 15, lg = lane >> 4;
  const int tN = blockIdx.x;  // 0..5  (fast dim)
  const int tM = blockIdx.y;  // 0..64
  const int r8 = lane >> 3;
  const int swch = (lane & 7) ^ r8;
  const int lr7 = lr & 7;

  const f16* Ab = Ah + ((size_t)tM * 128 + r8) * DIM + swch * 8;
  const f16* Bb = Bh + ((size_t)tN * 128 + r8) * DIM + swch * 8;

#pragma unroll
  for (int pp = 0; pp < 4; pp++) {
    int rowb = w * 32 + pp * 8;
    gl_lds16(Ab + (size_t)rowb * DIM, &As[0][rowb][0]);
    gl_lds16(Bb + (size_t)rowb * DIM, &Bs[0][rowb][0]);
  }

  f32x4 acc[4][4] = {};

  for (int kt = 0; kt < 12; kt++) {
    const int bi = kt & 1;
    DMA_FENCE;
    __syncthreads();
    if (kt + 1 < 12) {
#pragma unroll
      for (int pp = 0; pp < 4; pp++) {
        int rowb = w * 32 + pp * 8;
        gl_lds16(Ab + (size_t)rowb * DIM + (kt + 1) * 64, &As[bi ^ 1][rowb][0]);
        gl_lds16(Bb + (size_t)rowb * DIM + (kt + 1) * 64, &Bs[bi ^ 1][rowb][0]);
      }
    }
#pragma unroll
    for (int ks = 0; ks < 2; ks++) {
      f16x8 af[4], bf[4];
      int rc = ((ks * 4 + lg) ^ lr7) * 8;
#pragma unroll
      for (int i = 0; i < 4; i++) {
        af[i] = *(const f16x8*)(&As[bi][wm * 64 + i * 16 + lr][rc]);
        bf[i] = *(const f16x8*)(&Bs[bi][wn * 64 + i * 16 + lr][rc]);
      }
#pragma unroll
      for (int mi = 0; mi < 4; mi++)
#pragma unroll
        for (int ni = 0; ni < 4; ni++)
          acc[mi][ni] = __builtin_amdgcn_mfma_f32_16x16x32_f16(
              af[mi], bf[ni], acc[mi][ni], 0, 0, 0);
    }
  }

#pragma unroll
  for (int mi = 0; mi < 4; mi++) {
#pragma unroll
    for (int ni = 0; ni < 4; ni++) {
      int n = tN * 128 + wn * 64 + ni * 16 + lr;
      float bias = pb[n];
#pragma unroll
      for (int r = 0; r < 4; r++) {
        int m = tM * 128 + wm * 64 + mi * 16 + lg * 4 + r;
        if (m >= MTOT) continue;
        out[(size_t)m * DIM + n] = acc[mi][ni][r] + bias;
      }
    }
  }
}

extern "C" void kernel_launch(void* const* d_in, const int* in_sizes, int n_in,
                              void* d_out, int out_size, void* d_ws,
                              size_t ws_size, hipStream_t stream) {
  const float* x = (const float*)d_in[0];
  const float* qkv_w = (const float*)d_in[1];
  const float* q_bias = (const float*)d_in[2];
  const float* v_bias = (const float*)d_in[3];
  const float* rpb = (const float*)d_in[4];
  const float* proj_w = (const float*)d_in[5];
  const float* proj_b = (const float*)d_in[6];
  float* out = (float*)d_out;

  f16* xh = (f16*)d_ws;                        // [MPAD,768]
  f16* wh = xh + (size_t)MPAD * DIM;           // [2304,768]
  f16* pwh = wh + (size_t)3 * DIM * DIM;       // [768,768]
  f16* qb = pwh + (size_t)DIM * DIM;           // [96,1152,64]
  f16* kb = qb + (size_t)BATCH * HEADS * NQP2 * HD;
  f16* vtb = kb + (size_t)BATCH * HEADS * NKP * HD;
  f16* ob = vtb + (size_t)BATCH * HEADS * NKP * HD;  // [MPAD,768]
  f16* tbl = ob + (size_t)MPAD * DIM;          // [12,17,1088,4,16]

  cast3<<<dim3(1024, 3), 256, 0, stream>>>(
      x, xh, MTOT * DIM, qkv_w, wh, 3 * DIM * DIM, proj_w, pwh, DIM * DIM);
  bias_pre<<<dim3(17 * 17, HEADS), 256, 0, stream>>>(rpb, tbl);
  qkv_gemm<<<dim3(18, 65), 256, 0, stream>>>(xh, wh, q_bias, v_bias, qb, kb,
                                             vtb);
  attn_kernel<<<dim3(BATCH * HEADS * 9), 256, 0, stream>>>(qb, kb, vtb, tbl,
                                                           ob);
  proj_gemm<<<dim3(6, 65), 256, 0, stream>>>(ob, pwh, proj_b, out);
}